// Round 4
// baseline (207.029 us; speedup 1.0000x reference)
//
#include <hip/hip_runtime.h>
#include <hip/hip_bf16.h>

#define B_ 4
#define N_ 2048
#define M_ 2048
#define C_ 256
#define H_ 8
#define DH_ 32
#define R_ 128

typedef __bf16 bf16x8 __attribute__((ext_vector_type(8)));
typedef float f32x4 __attribute__((ext_vector_type(4)));

#define QSCL 0.25503486f      // (1/sqrt(32)) * log2(e)
#define LOG2E 1.4426950408889634f
#define DTHR 11.5f            // defer-max threshold in log2 domain (~8 nats)

__device__ __forceinline__ float fast_exp2(float x) {
    float r;
    asm("v_exp_f32 %0, %1" : "=v"(r) : "v"(x));
    return r;
}

#define GLOAD_LDS4(gp, lp)                                            \
    __builtin_amdgcn_global_load_lds(                                 \
        (const __attribute__((address_space(1))) void*)(gp),          \
        (__attribute__((address_space(3))) void*)(lp), 4, 0, 0)

// ---------------- Kernel 0: W^T (f32 -> bf16) for Wq, Wk, Wv ----------------
__global__ __launch_bounds__(256) void wtrans_kernel(
    const float* __restrict__ Wq, const float* __restrict__ Wk,
    const float* __restrict__ Wv, __bf16* __restrict__ out)
{
    __shared__ float t[32][33];
    int pz = blockIdx.z;
    const float* W = pz == 0 ? Wq : (pz == 1 ? Wk : Wv);
    int j0 = blockIdx.x * 32, k0 = blockIdx.y * 32;
    int tx = threadIdx.x, ty = threadIdx.y;
#pragma unroll
    for (int i = 0; i < 4; ++i)
        t[ty + 8 * i][tx] = W[(k0 + ty + 8 * i) * C_ + j0 + tx];
    __syncthreads();
    __bf16* o = out + (size_t)pz * C_ * C_;
#pragma unroll
    for (int i = 0; i < 4; ++i)
        o[(j0 + ty + 8 * i) * C_ + k0 + tx] = (__bf16)t[tx][ty + 8 * i];
}

// ---------------- Kernel 1: projections X@W+b -> bf16 ----------------------
// pz=0: q (B,H,N,Dh) scaled by QSCL; pz=1: k (B,H,M,Dh); pz=2: v^T (B,H,Dh,M)
__global__ __launch_bounds__(256) void proj_kernel(
    const float* __restrict__ Xq, const float* __restrict__ Xk, const float* __restrict__ Xv,
    const float* __restrict__ bq, const float* __restrict__ bk, const float* __restrict__ bv,
    const __bf16* __restrict__ Wt,
    __bf16* __restrict__ qb, __bf16* __restrict__ kb, __bf16* __restrict__ vt)
{
    int pz = blockIdx.z;
    const float* X = pz == 0 ? Xq : (pz == 1 ? Xk : Xv);
    const float* bias = pz == 0 ? bq : (pz == 1 ? bk : bv);
    const __bf16* W = Wt + (size_t)pz * C_ * C_;

    int r0 = blockIdx.x * 64;
    int w = threadIdx.x >> 6, lane = threadIdx.x & 63;
    int lg = lane >> 4, lr = lane & 15;
    int rw = r0 + w * 16;

    f32x4 z = {0.f, 0.f, 0.f, 0.f};
    f32x4 acc[16];
#pragma unroll
    for (int ns = 0; ns < 16; ++ns) acc[ns] = z;

    for (int ks = 0; ks < 8; ++ks) {
        const float* ap = X + (size_t)(rw + lr) * C_ + ks * 32 + lg * 8;
        float4 a0 = *(const float4*)ap;
        float4 a1 = *(const float4*)(ap + 4);
        bf16x8 af;
        af[0] = (__bf16)a0.x; af[1] = (__bf16)a0.y; af[2] = (__bf16)a0.z; af[3] = (__bf16)a0.w;
        af[4] = (__bf16)a1.x; af[5] = (__bf16)a1.y; af[6] = (__bf16)a1.z; af[7] = (__bf16)a1.w;
        if (pz < 2) {
#pragma unroll
            for (int ns = 0; ns < 16; ++ns) {
                bf16x8 bfv = *(const bf16x8*)(W + (size_t)(ns * 16 + lr) * C_ + ks * 32 + lg * 8);
                acc[ns] = __builtin_amdgcn_mfma_f32_16x16x32_bf16(bfv, af, acc[ns], 0, 0, 0);
            }
        } else {
#pragma unroll
            for (int ns = 0; ns < 16; ++ns) {
                bf16x8 bfv = *(const bf16x8*)(W + (size_t)(ns * 16 + lr) * C_ + ks * 32 + lg * 8);
                acc[ns] = __builtin_amdgcn_mfma_f32_16x16x32_bf16(af, bfv, acc[ns], 0, 0, 0);
            }
        }
    }

    if (pz < 2) {
        int ng = rw + lr;
        int bb = ng >> 11, n = ng & (N_ - 1);
        unsigned short* dst = (unsigned short*)(pz == 0 ? qb : kb);
#pragma unroll
        for (int ns = 0; ns < 16; ++ns) {
            int j0b = ns * 16 + 4 * lg;
            float4 b4 = *(const float4*)(bias + j0b);
            int hh = j0b >> 5, d0 = j0b & 31;
            float v0 = acc[ns][0] + b4.x, v1 = acc[ns][1] + b4.y;
            float v2 = acc[ns][2] + b4.z, v3 = acc[ns][3] + b4.w;
            if (pz == 0) { v0 *= QSCL; v1 *= QSCL; v2 *= QSCL; v3 *= QSCL; }
            ushort4 pk;
            pk.x = __builtin_bit_cast(unsigned short, (__bf16)v0);
            pk.y = __builtin_bit_cast(unsigned short, (__bf16)v1);
            pk.z = __builtin_bit_cast(unsigned short, (__bf16)v2);
            pk.w = __builtin_bit_cast(unsigned short, (__bf16)v3);
            *(ushort4*)(dst + ((((size_t)bb * H_ + hh) * 2048 + n) * DH_ + d0)) = pk;
        }
    } else {
        int r = rw + lg * 4;
        int bb = r >> 11, n = r & (N_ - 1);
#pragma unroll
        for (int ns = 0; ns < 16; ++ns) {
            int j = ns * 16 + lr;
            float bj = bias[j];
            int hh = j >> 5, d = j & 31;
            ushort4 pk;
            pk.x = __builtin_bit_cast(unsigned short, (__bf16)(acc[ns][0] + bj));
            pk.y = __builtin_bit_cast(unsigned short, (__bf16)(acc[ns][1] + bj));
            pk.z = __builtin_bit_cast(unsigned short, (__bf16)(acc[ns][2] + bj));
            pk.w = __builtin_bit_cast(unsigned short, (__bf16)(acc[ns][3] + bj));
            *(ushort4*)((unsigned short*)vt + (((size_t)bb * H_ + hh) * DH_ + d) * M_ + n) = pk;
        }
    }
}

// ---------------- Kernel 2: fused LRPE flash attention (M-split 2-way) ------
// grid 1024 = (b, qtile, mhalf), block 512 (8 waves = 8 heads).
// Writes unnormalized partial O + (m,l) stats; merge kernel combines halves.
__global__ __launch_bounds__(512, 8) void attn_kernel(
    const __bf16* __restrict__ qb, const __bf16* __restrict__ kb,
    const __bf16* __restrict__ vt, const int* __restrict__ ridx,
    const float* __restrict__ kmask, const float* __restrict__ rbank,
    float* __restrict__ Opart, float* __restrict__ Ms, float* __restrict__ Ls)
{
    __shared__ __bf16 Pall[H_][16][R_];   // 32 KB
    __shared__ int idxS[2][16 * 64];      // 8 KB, double-buffered, XOR-swizzled

    int lin = blockIdx.x;
    int mh = lin & 1;                     // M-half
    int b = (lin & 7) >> 1;               // (b, mh) pinned per XCD for K/V L2 locality
    int xq = lin >> 3;
    int n0 = xq * 16;
    int mbase = mh * (M_ / 2);

    int h = threadIdx.x >> 6, lane = threadIdx.x & 63;
    int lg = lane >> 4, lr = lane & 15;
    f32x4 z = {0.f, 0.f, 0.f, 0.f};

    const int* ixblk = ridx + ((size_t)b * N_ + n0) * M_;

    // ---- stage idx tile 0 (async) before Pall compute ----
#pragma unroll
    for (int i = 0; i < 2; ++i) {
        int r = 2 * h + i;
        int sw = 4 * (r & 7);
        GLOAD_LDS4(ixblk + (size_t)r * M_ + mbase + (lane ^ sw), &idxS[0][r * 64]);
    }

    // Q fragment (B-operand: col n = lr, k = 8*lg..+8); pre-scaled by QSCL
    bf16x8 qf = *(const bf16x8*)(qb + (((size_t)b * H_ + h) * N_ + n0 + lr) * DH_ + lg * 8);

    // P_all = Q @ rpe_h^T (16 x 128), own head only
    for (int rs = 0; rs < R_ / 16; ++rs) {
        const float* rp = rbank + (size_t)(rs * 16 + lr) * C_ + h * DH_ + lg * 8;
        float4 r0v = *(const float4*)rp;
        float4 r1v = *(const float4*)(rp + 4);
        bf16x8 rf;
        rf[0] = (__bf16)r0v.x; rf[1] = (__bf16)r0v.y; rf[2] = (__bf16)r0v.z; rf[3] = (__bf16)r0v.w;
        rf[4] = (__bf16)r1v.x; rf[5] = (__bf16)r1v.y; rf[6] = (__bf16)r1v.z; rf[7] = (__bf16)r1v.w;
        f32x4 pc = __builtin_amdgcn_mfma_f32_16x16x32_bf16(qf, rf, z, 0, 0, 0);
#pragma unroll
        for (int reg = 0; reg < 4; ++reg)
            Pall[h][lg * 4 + reg][rs * 16 + lr] = (__bf16)pc[reg];
    }

    __syncthreads();   // idx tile 0 landed + Pall visible

    const __bf16* Kh = kb + ((size_t)b * H_ + h) * M_ * DH_;
    const __bf16* Vh = vt + ((size_t)b * H_ + h) * DH_ * M_;
    const float* km = kmask + (size_t)b * M_;
    const __bf16* PallR = &Pall[h][lr][0];
    int swzR = 4 * (lr & 7);

    float mrow = -1e30f, lrun = 0.f;
    f32x4 acc[2] = {z, z};
    int cb = 0;

    for (int mt = 0; mt < 16; ++mt) {
        int m0 = mbase + mt * 64;
        int m0n = (mt < 15) ? m0 + 64 : m0;

        // (1) stage next idx tile (async; lands by end-of-tile barrier)
#pragma unroll
        for (int i = 0; i < 2; ++i) {
            int r = 2 * h + i;
            int sw = 4 * (r & 7);
            GLOAD_LDS4(ixblk + (size_t)r * M_ + m0n + (lane ^ sw), &idxS[cb ^ 1][r * 64]);
        }

        // K / V / mask loads for this tile
        bf16x8 kf[4];
#pragma unroll
        for (int ms = 0; ms < 4; ++ms)
            kf[ms] = *(const bf16x8*)(Kh + (size_t)(m0 + ms * 16 + lr) * DH_ + lg * 8);
        bf16x8 vf[4];
#pragma unroll
        for (int ds = 0; ds < 2; ++ds)
#pragma unroll
            for (int ks = 0; ks < 2; ++ks)
                vf[ds * 2 + ks] = *(const bf16x8*)(Vh + (size_t)(ds * 16 + lr) * M_ + m0 + ks * 32 + lg * 8);
        float4 mkv[4];
#pragma unroll
        for (int ms = 0; ms < 4; ++ms)
            mkv[ms] = *(const float4*)(km + m0 + ms * 16 + 4 * lg);

        // (2) idx (swizzled b128) + Pall gather
        int4 ixv[4];
#pragma unroll
        for (int ms = 0; ms < 4; ++ms)
            ixv[ms] = *(const int4*)&idxS[cb][lr * 64 + ((16 * ms + 4 * lg) ^ swzR)];
        float sv[16];
#pragma unroll
        for (int ms = 0; ms < 4; ++ms) {
            sv[ms * 4 + 0] = (float)PallR[ixv[ms].x];
            sv[ms * 4 + 1] = (float)PallR[ixv[ms].y];
            sv[ms * 4 + 2] = (float)PallR[ixv[ms].z];
            sv[ms * 4 + 3] = (float)PallR[ixv[ms].w];
        }

        // (3) S^T = K @ Q^T : D[row=m][col=n=lr]  (log2 domain)
        f32x4 st[4];
#pragma unroll
        for (int ms = 0; ms < 4; ++ms)
            st[ms] = __builtin_amdgcn_mfma_f32_16x16x32_bf16(kf[ms], qf, z, 0, 0, 0);

#pragma unroll
        for (int ms = 0; ms < 4; ++ms) {
            sv[ms * 4 + 0] = fmaf(mkv[ms].x, LOG2E, st[ms][0] + sv[ms * 4 + 0]);
            sv[ms * 4 + 1] = fmaf(mkv[ms].y, LOG2E, st[ms][1] + sv[ms * 4 + 1]);
            sv[ms * 4 + 2] = fmaf(mkv[ms].z, LOG2E, st[ms][2] + sv[ms * 4 + 2]);
            sv[ms * 4 + 3] = fmaf(mkv[ms].w, LOG2E, st[ms][3] + sv[ms * 4 + 3]);
        }

        // (4) softmax: lane-local max over 16 m + 2 shfl across groups
        float pmax = sv[0];
#pragma unroll
        for (int j = 1; j < 16; ++j) pmax = fmaxf(pmax, sv[j]);
        pmax = fmaxf(pmax, __shfl_xor(pmax, 16));
        pmax = fmaxf(pmax, __shfl_xor(pmax, 32));

        if (!__all(pmax - mrow <= DTHR)) {
            float mnew = fmaxf(mrow, pmax);
            float alpha = fast_exp2(mrow - mnew);
            mrow = mnew;
            lrun *= alpha;
#pragma unroll
            for (int reg = 0; reg < 4; ++reg) {
                float aB = __shfl(alpha, lg * 4 + reg);
                acc[0][reg] *= aB;
                acc[1][reg] *= aB;
            }
        }

        float pq[16], ssum = 0.f;
#pragma unroll
        for (int j = 0; j < 16; ++j) {
            pq[j] = fast_exp2(sv[j] - mrow);
            ssum += pq[j];
        }
        ssum += __shfl_xor(ssum, 16);
        ssum += __shfl_xor(ssum, 32);
        lrun += ssum;

        // (5) pack P^T pairs; redistribute to A-frag layout via shfl
        unsigned int pw[8];
#pragma unroll
        for (int p = 0; p < 8; ++p) {
            unsigned int lo = __builtin_bit_cast(unsigned short, (__bf16)pq[2 * p]);
            unsigned int hi = __builtin_bit_cast(unsigned short, (__bf16)pq[2 * p + 1]);
            pw[p] = lo | (hi << 16);
        }
        bool hiHalf = lane >= 32;
#pragma unroll
        for (int ks = 0; ks < 2; ++ks) {
            uint4 wv;
            unsigned int* wp = (unsigned int*)&wv;
#pragma unroll
            for (int wi = 0; wi < 4; ++wi) {
                int src = (((2 * lg + (wi >> 1)) & 3) << 4) + lr;
                unsigned int a0 = __shfl(pw[4 * ks + (wi & 1)], src);
                unsigned int a1 = __shfl(pw[4 * ks + 2 + (wi & 1)], src);
                wp[wi] = hiHalf ? a1 : a0;
            }
            bf16x8 pf = __builtin_bit_cast(bf16x8, wv);
#pragma unroll
            for (int ds = 0; ds < 2; ++ds)
                acc[ds] = __builtin_amdgcn_mfma_f32_16x16x32_bf16(pf, vf[ds * 2 + ks], acc[ds], 0, 0, 0);
        }

        // (6) one barrier per tile (vmcnt drain covers idx stage)
        __syncthreads();
        cb ^= 1;
    }

    // epilogue: unnormalized partial O + stats
    float* Op = Opart + ((((size_t)mh * B_ + b) * N_ + n0)) * C_ + h * DH_;
#pragma unroll
    for (int reg = 0; reg < 4; ++reg) {
        size_t rb = (size_t)(4 * lg + reg) * C_;
        Op[rb + lr] = acc[0][reg];
        Op[rb + 16 + lr] = acc[1][reg];
    }
    if (lane < 16) {
        size_t si = (((size_t)mh * B_ + b) * H_ + h) * N_ + n0 + lr;
        Ms[si] = mrow;
        Ls[si] = lrun;
    }
}

// ---------------- Kernel 3: merge the two M-halves --------------------------
__global__ __launch_bounds__(256) void merge_kernel(
    const float* __restrict__ Opart, const float* __restrict__ Ms,
    const float* __restrict__ Ls, float* __restrict__ out)
{
    int t = blockIdx.x * 256 + threadIdx.x;   // 524288 threads, float4 each
    int c4 = t & 63;
    int n = (t >> 6) & (N_ - 1);
    int bb = t >> 17;
    int h = c4 >> 3;

    size_t s0 = ((size_t)bb * H_ + h) * N_ + n;
    size_t s1 = (((size_t)B_ + bb) * H_ + h) * N_ + n;
    float m0 = Ms[s0], m1 = Ms[s1];
    float l0 = Ls[s0], l1 = Ls[s1];
    float mm = fmaxf(m0, m1);
    float w0 = fast_exp2(m0 - mm), w1 = fast_exp2(m1 - mm);
    float inv = 1.0f / (l0 * w0 + l1 * w1);
    w0 *= inv; w1 *= inv;

    size_t o0i = ((size_t)bb * N_ + n) * C_ + c4 * 4;
    size_t o1i = (((size_t)B_ + bb) * N_ + n) * C_ + c4 * 4;
    float4 o0 = *(const float4*)(Opart + o0i);
    float4 o1 = *(const float4*)(Opart + o1i);
    float4 r;
    r.x = o0.x * w0 + o1.x * w1;
    r.y = o0.y * w0 + o1.y * w1;
    r.z = o0.z * w0 + o1.z * w1;
    r.w = o0.w * w0 + o1.w * w1;
    *(float4*)(out + ((size_t)bb * N_ + n) * C_ + c4 * 4) = r;
}

// ---------------- launch ----------------------------------------------------
extern "C" void kernel_launch(void* const* d_in, const int* in_sizes, int n_in,
                              void* d_out, int out_size, void* d_ws, size_t ws_size,
                              hipStream_t stream) {
    const float* Xq = (const float*)d_in[0];
    const float* Xk = (const float*)d_in[1];
    const float* Xv = (const float*)d_in[2];
    const int* ridx = (const int*)d_in[3];
    const float* kmask = (const float*)d_in[4];
    const float* Wq = (const float*)d_in[5];
    const float* bq = (const float*)d_in[6];
    const float* Wk = (const float*)d_in[7];
    const float* bk = (const float*)d_in[8];
    const float* Wv = (const float*)d_in[9];
    const float* bv = (const float*)d_in[10];
    const float* rbank = (const float*)d_in[11];
    float* outp = (float*)d_out;

    char* ws = (char*)d_ws;
    __bf16* Wt = (__bf16*)ws;                               // 393216 B
    __bf16* qb = (__bf16*)(ws + 393216);                    // 4 MB
    __bf16* kb = (__bf16*)(ws + 393216 + 4194304);          // 4 MB
    __bf16* vt = (__bf16*)(ws + 393216 + 8388608);          // 4 MB
    float* Opart = (float*)(ws + 12976128);                 // 16 MB (2 halves)
    float* Msb = (float*)(ws + 12976128 + 16777216);        // 512 KB
    float* Lsb = (float*)(ws + 12976128 + 16777216 + 524288); // 512 KB

    wtrans_kernel<<<dim3(8, 8, 3), dim3(32, 8), 0, stream>>>(Wq, Wk, Wv, Wt);
    proj_kernel<<<dim3(128, 1, 3), 256, 0, stream>>>(Xq, Xk, Xv, bq, bk, bv, Wt, qb, kb, vt);
    attn_kernel<<<1024, 512, 0, stream>>>(qb, kb, vt, ridx, kmask, rbank, Opart, Msb, Lsb);
    merge_kernel<<<2048, 256, 0, stream>>>(Opart, Msb, Lsb, outp);
}

// Round 5
// 191.932 us; speedup vs baseline: 1.0787x; 1.0787x over previous
//
#include <hip/hip_runtime.h>
#include <hip/hip_bf16.h>

#define B_ 4
#define N_ 2048
#define M_ 2048
#define C_ 256
#define H_ 8
#define DH_ 32
#define R_ 128

typedef __bf16 bf16x8 __attribute__((ext_vector_type(8)));
typedef float f32x4 __attribute__((ext_vector_type(4)));

#define QSCL 0.25503486f      // (1/sqrt(32)) * log2(e)
#define LOG2E 1.4426950408889634f
#define DTHR 11.5f            // defer-max threshold in log2 domain (~8 nats)

__device__ __forceinline__ float fast_exp2(float x) {
    float r;
    asm("v_exp_f32 %0, %1" : "=v"(r) : "v"(x));
    return r;
}

#define GLOAD_LDS4(gp, lp)                                            \
    __builtin_amdgcn_global_load_lds(                                 \
        (const __attribute__((address_space(1))) void*)(gp),          \
        (__attribute__((address_space(3))) void*)(lp), 4, 0, 0)

// ---------------- Kernel 0: W^T (f32 -> bf16) for Wq, Wk, Wv ----------------
__global__ __launch_bounds__(256) void wtrans_kernel(
    const float* __restrict__ Wq, const float* __restrict__ Wk,
    const float* __restrict__ Wv, __bf16* __restrict__ out)
{
    __shared__ float t[32][33];
    int pz = blockIdx.z;
    const float* W = pz == 0 ? Wq : (pz == 1 ? Wk : Wv);
    int j0 = blockIdx.x * 32, k0 = blockIdx.y * 32;
    int tx = threadIdx.x, ty = threadIdx.y;
#pragma unroll
    for (int i = 0; i < 4; ++i)
        t[ty + 8 * i][tx] = W[(k0 + ty + 8 * i) * C_ + j0 + tx];
    __syncthreads();
    __bf16* o = out + (size_t)pz * C_ * C_;
#pragma unroll
    for (int i = 0; i < 4; ++i)
        o[(j0 + ty + 8 * i) * C_ + k0 + tx] = (__bf16)t[tx][ty + 8 * i];
}

// ---------------- Kernel 1: projections X@W+b -> bf16 ----------------------
// pz=0: q (B,H,N,Dh) scaled by QSCL; pz=1: k (B,H,M,Dh); pz=2: v^T (B,H,Dh,M)
__global__ __launch_bounds__(256) void proj_kernel(
    const float* __restrict__ Xq, const float* __restrict__ Xk, const float* __restrict__ Xv,
    const float* __restrict__ bq, const float* __restrict__ bk, const float* __restrict__ bv,
    const __bf16* __restrict__ Wt,
    __bf16* __restrict__ qb, __bf16* __restrict__ kb, __bf16* __restrict__ vt)
{
    int pz = blockIdx.z;
    const float* X = pz == 0 ? Xq : (pz == 1 ? Xk : Xv);
    const float* bias = pz == 0 ? bq : (pz == 1 ? bk : bv);
    const __bf16* W = Wt + (size_t)pz * C_ * C_;

    int r0 = blockIdx.x * 64;
    int w = threadIdx.x >> 6, lane = threadIdx.x & 63;
    int lg = lane >> 4, lr = lane & 15;
    int rw = r0 + w * 16;

    f32x4 z = {0.f, 0.f, 0.f, 0.f};
    f32x4 acc[16];
#pragma unroll
    for (int ns = 0; ns < 16; ++ns) acc[ns] = z;

    for (int ks = 0; ks < 8; ++ks) {
        const float* ap = X + (size_t)(rw + lr) * C_ + ks * 32 + lg * 8;
        float4 a0 = *(const float4*)ap;
        float4 a1 = *(const float4*)(ap + 4);
        bf16x8 af;
        af[0] = (__bf16)a0.x; af[1] = (__bf16)a0.y; af[2] = (__bf16)a0.z; af[3] = (__bf16)a0.w;
        af[4] = (__bf16)a1.x; af[5] = (__bf16)a1.y; af[6] = (__bf16)a1.z; af[7] = (__bf16)a1.w;
        if (pz < 2) {
#pragma unroll
            for (int ns = 0; ns < 16; ++ns) {
                bf16x8 bfv = *(const bf16x8*)(W + (size_t)(ns * 16 + lr) * C_ + ks * 32 + lg * 8);
                acc[ns] = __builtin_amdgcn_mfma_f32_16x16x32_bf16(bfv, af, acc[ns], 0, 0, 0);
            }
        } else {
#pragma unroll
            for (int ns = 0; ns < 16; ++ns) {
                bf16x8 bfv = *(const bf16x8*)(W + (size_t)(ns * 16 + lr) * C_ + ks * 32 + lg * 8);
                acc[ns] = __builtin_amdgcn_mfma_f32_16x16x32_bf16(af, bfv, acc[ns], 0, 0, 0);
            }
        }
    }

    if (pz < 2) {
        int ng = rw + lr;
        int bb = ng >> 11, n = ng & (N_ - 1);
        unsigned short* dst = (unsigned short*)(pz == 0 ? qb : kb);
#pragma unroll
        for (int ns = 0; ns < 16; ++ns) {
            int j0b = ns * 16 + 4 * lg;
            float4 b4 = *(const float4*)(bias + j0b);
            int hh = j0b >> 5, d0 = j0b & 31;
            float v0 = acc[ns][0] + b4.x, v1 = acc[ns][1] + b4.y;
            float v2 = acc[ns][2] + b4.z, v3 = acc[ns][3] + b4.w;
            if (pz == 0) { v0 *= QSCL; v1 *= QSCL; v2 *= QSCL; v3 *= QSCL; }
            ushort4 pk;
            pk.x = __builtin_bit_cast(unsigned short, (__bf16)v0);
            pk.y = __builtin_bit_cast(unsigned short, (__bf16)v1);
            pk.z = __builtin_bit_cast(unsigned short, (__bf16)v2);
            pk.w = __builtin_bit_cast(unsigned short, (__bf16)v3);
            *(ushort4*)(dst + ((((size_t)bb * H_ + hh) * 2048 + n) * DH_ + d0)) = pk;
        }
    } else {
        int r = rw + lg * 4;
        int bb = r >> 11, n = r & (N_ - 1);
#pragma unroll
        for (int ns = 0; ns < 16; ++ns) {
            int j = ns * 16 + lr;
            float bj = bias[j];
            int hh = j >> 5, d = j & 31;
            ushort4 pk;
            pk.x = __builtin_bit_cast(unsigned short, (__bf16)(acc[ns][0] + bj));
            pk.y = __builtin_bit_cast(unsigned short, (__bf16)(acc[ns][1] + bj));
            pk.z = __builtin_bit_cast(unsigned short, (__bf16)(acc[ns][2] + bj));
            pk.w = __builtin_bit_cast(unsigned short, (__bf16)(acc[ns][3] + bj));
            *(ushort4*)((unsigned short*)vt + (((size_t)bb * H_ + hh) * DH_ + d) * M_ + n) = pk;
        }
    }
}

// ---------------- Kernel 2: fused LRPE flash attention (M-split 2-way) ------
// grid 1024 = (b, qtile, mhalf), block 512 (8 waves = 8 heads).
// NO min-waves clause: round 4's (512,8) forced VGPR->32 and spilled.
__global__ __launch_bounds__(512) void attn_kernel(
    const __bf16* __restrict__ qb, const __bf16* __restrict__ kb,
    const __bf16* __restrict__ vt, const int* __restrict__ ridx,
    const float* __restrict__ kmask, const float* __restrict__ rbank,
    float* __restrict__ Opart, float* __restrict__ Ms, float* __restrict__ Ls)
{
    __shared__ __bf16 Pall[H_][16][R_];   // 32 KB
    __shared__ int idxS[2][16 * 64];      // 8 KB, double-buffered, XOR-swizzled

    int lin = blockIdx.x;
    int mh = lin & 1;                     // M-half
    int b = (lin & 7) >> 1;               // (b, mh) pinned per XCD for K/V L2 locality
    int xq = lin >> 3;
    int n0 = xq * 16;
    int mbase = mh * (M_ / 2);

    int h = threadIdx.x >> 6, lane = threadIdx.x & 63;
    int lg = lane >> 4, lr = lane & 15;
    f32x4 z = {0.f, 0.f, 0.f, 0.f};

    const int* ixblk = ridx + ((size_t)b * N_ + n0) * M_;

    // ---- stage idx tile 0 (async) before Pall compute ----
#pragma unroll
    for (int i = 0; i < 2; ++i) {
        int r = 2 * h + i;
        int sw = 4 * (r & 7);
        GLOAD_LDS4(ixblk + (size_t)r * M_ + mbase + (lane ^ sw), &idxS[0][r * 64]);
    }

    // Q fragment (B-operand: col n = lr, k = 8*lg..+8); pre-scaled by QSCL
    bf16x8 qf = *(const bf16x8*)(qb + (((size_t)b * H_ + h) * N_ + n0 + lr) * DH_ + lg * 8);

    // P_all = Q @ rpe_h^T (16 x 128), own head only
    for (int rs = 0; rs < R_ / 16; ++rs) {
        const float* rp = rbank + (size_t)(rs * 16 + lr) * C_ + h * DH_ + lg * 8;
        float4 r0v = *(const float4*)rp;
        float4 r1v = *(const float4*)(rp + 4);
        bf16x8 rf;
        rf[0] = (__bf16)r0v.x; rf[1] = (__bf16)r0v.y; rf[2] = (__bf16)r0v.z; rf[3] = (__bf16)r0v.w;
        rf[4] = (__bf16)r1v.x; rf[5] = (__bf16)r1v.y; rf[6] = (__bf16)r1v.z; rf[7] = (__bf16)r1v.w;
        f32x4 pc = __builtin_amdgcn_mfma_f32_16x16x32_bf16(qf, rf, z, 0, 0, 0);
#pragma unroll
        for (int reg = 0; reg < 4; ++reg)
            Pall[h][lg * 4 + reg][rs * 16 + lr] = (__bf16)pc[reg];
    }

    __syncthreads();   // idx tile 0 landed + Pall visible

    const __bf16* Kh = kb + ((size_t)b * H_ + h) * M_ * DH_;
    const __bf16* Vh = vt + ((size_t)b * H_ + h) * DH_ * M_;
    const float* km = kmask + (size_t)b * M_;
    const __bf16* PallR = &Pall[h][lr][0];
    int swzR = 4 * (lr & 7);

    float mrow = -1e30f, lrun = 0.f;
    f32x4 acc[2] = {z, z};
    int cb = 0;

    for (int mt = 0; mt < 16; ++mt) {
        int m0 = mbase + mt * 64;
        int m0n = (mt < 15) ? m0 + 64 : m0;

        // (1) stage next idx tile (async; lands by end-of-tile barrier)
#pragma unroll
        for (int i = 0; i < 2; ++i) {
            int r = 2 * h + i;
            int sw = 4 * (r & 7);
            GLOAD_LDS4(ixblk + (size_t)r * M_ + m0n + (lane ^ sw), &idxS[cb ^ 1][r * 64]);
        }

        // K / V / mask loads for this tile
        bf16x8 kf[4];
#pragma unroll
        for (int ms = 0; ms < 4; ++ms)
            kf[ms] = *(const bf16x8*)(Kh + (size_t)(m0 + ms * 16 + lr) * DH_ + lg * 8);
        bf16x8 vf[4];
#pragma unroll
        for (int ds = 0; ds < 2; ++ds)
#pragma unroll
            for (int ks = 0; ks < 2; ++ks)
                vf[ds * 2 + ks] = *(const bf16x8*)(Vh + (size_t)(ds * 16 + lr) * M_ + m0 + ks * 32 + lg * 8);
        float4 mkv[4];
#pragma unroll
        for (int ms = 0; ms < 4; ++ms)
            mkv[ms] = *(const float4*)(km + m0 + ms * 16 + 4 * lg);

        // (2) idx (swizzled b128) + Pall gather
        int4 ixv[4];
#pragma unroll
        for (int ms = 0; ms < 4; ++ms)
            ixv[ms] = *(const int4*)&idxS[cb][lr * 64 + ((16 * ms + 4 * lg) ^ swzR)];
        float sv[16];
#pragma unroll
        for (int ms = 0; ms < 4; ++ms) {
            sv[ms * 4 + 0] = (float)PallR[ixv[ms].x];
            sv[ms * 4 + 1] = (float)PallR[ixv[ms].y];
            sv[ms * 4 + 2] = (float)PallR[ixv[ms].z];
            sv[ms * 4 + 3] = (float)PallR[ixv[ms].w];
        }

        // (3) S^T = K @ Q^T : D[row=m][col=n=lr]  (log2 domain)
        f32x4 st[4];
#pragma unroll
        for (int ms = 0; ms < 4; ++ms)
            st[ms] = __builtin_amdgcn_mfma_f32_16x16x32_bf16(kf[ms], qf, z, 0, 0, 0);

#pragma unroll
        for (int ms = 0; ms < 4; ++ms) {
            sv[ms * 4 + 0] = fmaf(mkv[ms].x, LOG2E, st[ms][0] + sv[ms * 4 + 0]);
            sv[ms * 4 + 1] = fmaf(mkv[ms].y, LOG2E, st[ms][1] + sv[ms * 4 + 1]);
            sv[ms * 4 + 2] = fmaf(mkv[ms].z, LOG2E, st[ms][2] + sv[ms * 4 + 2]);
            sv[ms * 4 + 3] = fmaf(mkv[ms].w, LOG2E, st[ms][3] + sv[ms * 4 + 3]);
        }

        // (4) softmax: lane-local max over 16 m + 2 shfl across groups
        float pmax = sv[0];
#pragma unroll
        for (int j = 1; j < 16; ++j) pmax = fmaxf(pmax, sv[j]);
        pmax = fmaxf(pmax, __shfl_xor(pmax, 16));
        pmax = fmaxf(pmax, __shfl_xor(pmax, 32));

        if (!__all(pmax - mrow <= DTHR)) {
            float mnew = fmaxf(mrow, pmax);
            float alpha = fast_exp2(mrow - mnew);
            mrow = mnew;
            lrun *= alpha;
#pragma unroll
            for (int reg = 0; reg < 4; ++reg) {
                float aB = __shfl(alpha, lg * 4 + reg);
                acc[0][reg] *= aB;
                acc[1][reg] *= aB;
            }
        }

        float pq[16], ssum = 0.f;
#pragma unroll
        for (int j = 0; j < 16; ++j) {
            pq[j] = fast_exp2(sv[j] - mrow);
            ssum += pq[j];
        }
        ssum += __shfl_xor(ssum, 16);
        ssum += __shfl_xor(ssum, 32);
        lrun += ssum;

        // (5) pack P^T pairs; redistribute to A-frag layout via shfl
        unsigned int pw[8];
#pragma unroll
        for (int p = 0; p < 8; ++p) {
            unsigned int lo = __builtin_bit_cast(unsigned short, (__bf16)pq[2 * p]);
            unsigned int hi = __builtin_bit_cast(unsigned short, (__bf16)pq[2 * p + 1]);
            pw[p] = lo | (hi << 16);
        }
        bool hiHalf = lane >= 32;
#pragma unroll
        for (int ks = 0; ks < 2; ++ks) {
            uint4 wv;
            unsigned int* wp = (unsigned int*)&wv;
#pragma unroll
            for (int wi = 0; wi < 4; ++wi) {
                int src = (((2 * lg + (wi >> 1)) & 3) << 4) + lr;
                unsigned int a0 = __shfl(pw[4 * ks + (wi & 1)], src);
                unsigned int a1 = __shfl(pw[4 * ks + 2 + (wi & 1)], src);
                wp[wi] = hiHalf ? a1 : a0;
            }
            bf16x8 pf = __builtin_bit_cast(bf16x8, wv);
#pragma unroll
            for (int ds = 0; ds < 2; ++ds)
                acc[ds] = __builtin_amdgcn_mfma_f32_16x16x32_bf16(pf, vf[ds * 2 + ks], acc[ds], 0, 0, 0);
        }

        // (6) one barrier per tile (vmcnt drain covers idx stage)
        __syncthreads();
        cb ^= 1;
    }

    // epilogue: unnormalized partial O + stats
    float* Op = Opart + ((((size_t)mh * B_ + b) * N_ + n0)) * C_ + h * DH_;
#pragma unroll
    for (int reg = 0; reg < 4; ++reg) {
        size_t rb = (size_t)(4 * lg + reg) * C_;
        Op[rb + lr] = acc[0][reg];
        Op[rb + 16 + lr] = acc[1][reg];
    }
    if (lane < 16) {
        size_t si = (((size_t)mh * B_ + b) * H_ + h) * N_ + n0 + lr;
        Ms[si] = mrow;
        Ls[si] = lrun;
    }
}

// ---------------- Kernel 3: merge the two M-halves --------------------------
__global__ __launch_bounds__(256) void merge_kernel(
    const float* __restrict__ Opart, const float* __restrict__ Ms,
    const float* __restrict__ Ls, float* __restrict__ out)
{
    int t = blockIdx.x * 256 + threadIdx.x;   // 524288 threads, float4 each
    int c4 = t & 63;
    int n = (t >> 6) & (N_ - 1);
    int bb = t >> 17;
    int h = c4 >> 3;

    size_t s0 = ((size_t)bb * H_ + h) * N_ + n;
    size_t s1 = (((size_t)B_ + bb) * H_ + h) * N_ + n;
    float m0 = Ms[s0], m1 = Ms[s1];
    float l0 = Ls[s0], l1 = Ls[s1];
    float mm = fmaxf(m0, m1);
    float w0 = fast_exp2(m0 - mm), w1 = fast_exp2(m1 - mm);
    float inv = 1.0f / (l0 * w0 + l1 * w1);
    w0 *= inv; w1 *= inv;

    size_t o0i = ((size_t)bb * N_ + n) * C_ + c4 * 4;
    size_t o1i = (((size_t)B_ + bb) * N_ + n) * C_ + c4 * 4;
    float4 o0 = *(const float4*)(Opart + o0i);
    float4 o1 = *(const float4*)(Opart + o1i);
    float4 r;
    r.x = o0.x * w0 + o1.x * w1;
    r.y = o0.y * w0 + o1.y * w1;
    r.z = o0.z * w0 + o1.z * w1;
    r.w = o0.w * w0 + o1.w * w1;
    *(float4*)(out + ((size_t)bb * N_ + n) * C_ + c4 * 4) = r;
}

// ---------------- launch ----------------------------------------------------
extern "C" void kernel_launch(void* const* d_in, const int* in_sizes, int n_in,
                              void* d_out, int out_size, void* d_ws, size_t ws_size,
                              hipStream_t stream) {
    const float* Xq = (const float*)d_in[0];
    const float* Xk = (const float*)d_in[1];
    const float* Xv = (const float*)d_in[2];
    const int* ridx = (const int*)d_in[3];
    const float* kmask = (const float*)d_in[4];
    const float* Wq = (const float*)d_in[5];
    const float* bq = (const float*)d_in[6];
    const float* Wk = (const float*)d_in[7];
    const float* bk = (const float*)d_in[8];
    const float* Wv = (const float*)d_in[9];
    const float* bv = (const float*)d_in[10];
    const float* rbank = (const float*)d_in[11];
    float* outp = (float*)d_out;

    char* ws = (char*)d_ws;
    __bf16* Wt = (__bf16*)ws;                               // 393216 B
    __bf16* qb = (__bf16*)(ws + 393216);                    // 4 MB
    __bf16* kb = (__bf16*)(ws + 393216 + 4194304);          // 4 MB
    __bf16* vt = (__bf16*)(ws + 393216 + 8388608);          // 4 MB
    float* Opart = (float*)(ws + 12976128);                 // 16 MB (2 halves)
    float* Msb = (float*)(ws + 12976128 + 16777216);        // 512 KB
    float* Lsb = (float*)(ws + 12976128 + 16777216 + 524288); // 512 KB

    wtrans_kernel<<<dim3(8, 8, 3), dim3(32, 8), 0, stream>>>(Wq, Wk, Wv, Wt);
    proj_kernel<<<dim3(128, 1, 3), 256, 0, stream>>>(Xq, Xk, Xv, bq, bk, bv, Wt, qb, kb, vt);
    attn_kernel<<<1024, 512, 0, stream>>>(qb, kb, vt, ridx, kmask, rbank, Opart, Msb, Lsb);
    merge_kernel<<<2048, 256, 0, stream>>>(Opart, Msb, Lsb, outp);
}

// Round 6
// 171.745 us; speedup vs baseline: 1.2054x; 1.1175x over previous
//
#include <hip/hip_runtime.h>
#include <hip/hip_bf16.h>

#define B_ 4
#define N_ 2048
#define M_ 2048
#define C_ 256
#define H_ 8
#define DH_ 32
#define R_ 128

typedef __bf16 bf16x8 __attribute__((ext_vector_type(8)));
typedef float f32x4 __attribute__((ext_vector_type(4)));

#define QSCL 0.25503486f      // (1/sqrt(32)) * log2(e)
#define LOG2E 1.4426950408889634f
#define DTHR 11.5f            // defer-max threshold in log2 domain (~8 nats)

__device__ __forceinline__ float fast_exp2(float x) {
    float r;
    asm("v_exp_f32 %0, %1" : "=v"(r) : "v"(x));
    return r;
}

#define GLOAD_LDS4(gp, lp)                                            \
    __builtin_amdgcn_global_load_lds(                                 \
        (const __attribute__((address_space(1))) void*)(gp),          \
        (__attribute__((address_space(3))) void*)(lp), 4, 0, 0)

// ---------------- Kernel 0: W^T (f32 -> bf16) for Wq, Wk, Wv ----------------
__global__ __launch_bounds__(256) void wtrans_kernel(
    const float* __restrict__ Wq, const float* __restrict__ Wk,
    const float* __restrict__ Wv, __bf16* __restrict__ out)
{
    __shared__ float t[32][33];
    int pz = blockIdx.z;
    const float* W = pz == 0 ? Wq : (pz == 1 ? Wk : Wv);
    int j0 = blockIdx.x * 32, k0 = blockIdx.y * 32;
    int tx = threadIdx.x, ty = threadIdx.y;
#pragma unroll
    for (int i = 0; i < 4; ++i)
        t[ty + 8 * i][tx] = W[(k0 + ty + 8 * i) * C_ + j0 + tx];
    __syncthreads();
    __bf16* o = out + (size_t)pz * C_ * C_;
#pragma unroll
    for (int i = 0; i < 4; ++i)
        o[(j0 + ty + 8 * i) * C_ + k0 + tx] = (__bf16)t[tx][ty + 8 * i];
}

// ---------------- Kernel 1: projections X@W+b -> bf16 ----------------------
// pz=0: q (B,H,N,Dh) scaled by QSCL; pz=1: k (B,H,M,Dh)
// pz=2: v^T (B,H,Dh,M) with per-32-column PERMUTED order so PV needs no shuffle:
//   store col (m & ~31) | g<<3 | b<<2 | r   for m-local = 16b + 4g + r
__global__ __launch_bounds__(256) void proj_kernel(
    const float* __restrict__ Xq, const float* __restrict__ Xk, const float* __restrict__ Xv,
    const float* __restrict__ bq, const float* __restrict__ bk, const float* __restrict__ bv,
    const __bf16* __restrict__ Wt,
    __bf16* __restrict__ qb, __bf16* __restrict__ kb, __bf16* __restrict__ vt)
{
    int pz = blockIdx.z;
    const float* X = pz == 0 ? Xq : (pz == 1 ? Xk : Xv);
    const float* bias = pz == 0 ? bq : (pz == 1 ? bk : bv);
    const __bf16* W = Wt + (size_t)pz * C_ * C_;

    int r0 = blockIdx.x * 64;
    int w = threadIdx.x >> 6, lane = threadIdx.x & 63;
    int lg = lane >> 4, lr = lane & 15;
    int rw = r0 + w * 16;

    f32x4 z = {0.f, 0.f, 0.f, 0.f};
    f32x4 acc[16];
#pragma unroll
    for (int ns = 0; ns < 16; ++ns) acc[ns] = z;

    for (int ks = 0; ks < 8; ++ks) {
        const float* ap = X + (size_t)(rw + lr) * C_ + ks * 32 + lg * 8;
        float4 a0 = *(const float4*)ap;
        float4 a1 = *(const float4*)(ap + 4);
        bf16x8 af;
        af[0] = (__bf16)a0.x; af[1] = (__bf16)a0.y; af[2] = (__bf16)a0.z; af[3] = (__bf16)a0.w;
        af[4] = (__bf16)a1.x; af[5] = (__bf16)a1.y; af[6] = (__bf16)a1.z; af[7] = (__bf16)a1.w;
        if (pz < 2) {
#pragma unroll
            for (int ns = 0; ns < 16; ++ns) {
                bf16x8 bfv = *(const bf16x8*)(W + (size_t)(ns * 16 + lr) * C_ + ks * 32 + lg * 8);
                acc[ns] = __builtin_amdgcn_mfma_f32_16x16x32_bf16(bfv, af, acc[ns], 0, 0, 0);
            }
        } else {
#pragma unroll
            for (int ns = 0; ns < 16; ++ns) {
                bf16x8 bfv = *(const bf16x8*)(W + (size_t)(ns * 16 + lr) * C_ + ks * 32 + lg * 8);
                acc[ns] = __builtin_amdgcn_mfma_f32_16x16x32_bf16(af, bfv, acc[ns], 0, 0, 0);
            }
        }
    }

    if (pz < 2) {
        int ng = rw + lr;
        int bb = ng >> 11, n = ng & (N_ - 1);
        unsigned short* dst = (unsigned short*)(pz == 0 ? qb : kb);
#pragma unroll
        for (int ns = 0; ns < 16; ++ns) {
            int j0b = ns * 16 + 4 * lg;
            float4 b4 = *(const float4*)(bias + j0b);
            int hh = j0b >> 5, d0 = j0b & 31;
            float v0 = acc[ns][0] + b4.x, v1 = acc[ns][1] + b4.y;
            float v2 = acc[ns][2] + b4.z, v3 = acc[ns][3] + b4.w;
            if (pz == 0) { v0 *= QSCL; v1 *= QSCL; v2 *= QSCL; v3 *= QSCL; }
            ushort4 pk;
            pk.x = __builtin_bit_cast(unsigned short, (__bf16)v0);
            pk.y = __builtin_bit_cast(unsigned short, (__bf16)v1);
            pk.z = __builtin_bit_cast(unsigned short, (__bf16)v2);
            pk.w = __builtin_bit_cast(unsigned short, (__bf16)v3);
            *(ushort4*)(dst + ((((size_t)bb * H_ + hh) * 2048 + n) * DH_ + d0)) = pk;
        }
    } else {
        int r = rw + lg * 4;
        int bb = r >> 11, n = r & (N_ - 1);
        // permuted column so PV A-frag is lane-local: m-local 16b+4g+r -> 8g+4b+r
        int np = (n & ~31) | (((n >> 2) & 3) << 3) | (((n >> 4) & 1) << 2);
#pragma unroll
        for (int ns = 0; ns < 16; ++ns) {
            int j = ns * 16 + lr;
            float bj = bias[j];
            int hh = j >> 5, d = j & 31;
            ushort4 pk;
            pk.x = __builtin_bit_cast(unsigned short, (__bf16)(acc[ns][0] + bj));
            pk.y = __builtin_bit_cast(unsigned short, (__bf16)(acc[ns][1] + bj));
            pk.z = __builtin_bit_cast(unsigned short, (__bf16)(acc[ns][2] + bj));
            pk.w = __builtin_bit_cast(unsigned short, (__bf16)(acc[ns][3] + bj));
            *(ushort4*)((unsigned short*)vt + (((size_t)bb * H_ + hh) * DH_ + d) * M_ + np) = pk;
        }
    }
}

// ---------------- Kernel 2: fused LRPE flash attention ----------------------
// grid 512, block 512 (8 waves = 8 heads). Swapped QK^T: lane owns row n=lr.
// Zero cross-lane ops in the common path: lane-local defer-max check (__all),
// per-lane partial sum, permuted-V PV (pq feeds MFMA A-frag directly).
__global__ __launch_bounds__(512, 4) void attn_kernel(
    const __bf16* __restrict__ qb, const __bf16* __restrict__ kb,
    const __bf16* __restrict__ vt, const int* __restrict__ ridx,
    const float* __restrict__ kmask, const float* __restrict__ rbank,
    float* __restrict__ out)
{
    __shared__ __bf16 Pall[H_][16][R_];   // 32 KB
    __shared__ int idxS[2][16 * 64];      // 8 KB, double-buffered, XOR-swizzled

    int lin = blockIdx.x;
    int b = (lin & 7) >> 1;               // batch pinned per XCD pair (K/V L2 locality)
    int xq = ((lin >> 3) << 1) | (lin & 1);
    int n0 = xq * 16;

    int h = threadIdx.x >> 6, lane = threadIdx.x & 63;
    int lg = lane >> 4, lr = lane & 15;
    f32x4 z = {0.f, 0.f, 0.f, 0.f};

    const int* ixblk = ridx + ((size_t)b * N_ + n0) * M_;

    // ---- stage idx tile 0 (async) before Pall compute ----
#pragma unroll
    for (int i = 0; i < 2; ++i) {
        int r = 2 * h + i;
        int sw = 4 * (r & 7);
        GLOAD_LDS4(ixblk + (size_t)r * M_ + (lane ^ sw), &idxS[0][r * 64]);
    }

    // Q fragment (B-operand: col n = lr, k = 8*lg..+8); pre-scaled by QSCL
    bf16x8 qf = *(const bf16x8*)(qb + (((size_t)b * H_ + h) * N_ + n0 + lr) * DH_ + lg * 8);

    // P_all = Q @ rpe_h^T (16 x 128), own head only
    for (int rs = 0; rs < R_ / 16; ++rs) {
        const float* rp = rbank + (size_t)(rs * 16 + lr) * C_ + h * DH_ + lg * 8;
        float4 r0v = *(const float4*)rp;
        float4 r1v = *(const float4*)(rp + 4);
        bf16x8 rf;
        rf[0] = (__bf16)r0v.x; rf[1] = (__bf16)r0v.y; rf[2] = (__bf16)r0v.z; rf[3] = (__bf16)r0v.w;
        rf[4] = (__bf16)r1v.x; rf[5] = (__bf16)r1v.y; rf[6] = (__bf16)r1v.z; rf[7] = (__bf16)r1v.w;
        f32x4 pc = __builtin_amdgcn_mfma_f32_16x16x32_bf16(qf, rf, z, 0, 0, 0);
#pragma unroll
        for (int reg = 0; reg < 4; ++reg)
            Pall[h][lg * 4 + reg][rs * 16 + lr] = (__bf16)pc[reg];
    }

    const __bf16* Kh = kb + ((size_t)b * H_ + h) * M_ * DH_;
    const __bf16* Vh = vt + ((size_t)b * H_ + h) * DH_ * M_;
    const float* km = kmask + (size_t)b * M_;
    const __bf16* PallR = &Pall[h][lr][0];
    int swzR = 4 * (lr & 7);

    // prefetch K for tile 0
    bf16x8 kf[4];
#pragma unroll
    for (int ms = 0; ms < 4; ++ms)
        kf[ms] = *(const bf16x8*)(Kh + (size_t)(ms * 16 + lr) * DH_ + lg * 8);

    __syncthreads();   // idx tile 0 landed + Pall visible

    float mrow = -1e30f, lloc = 0.f;
    f32x4 acc[2] = {z, z};
    int cb = 0;

#pragma unroll 2
    for (int mt = 0; mt < M_ / 64; ++mt) {
        int m0 = mt * 64;
        int m0n = (mt < 31) ? m0 + 64 : m0;

        // (1) stage next idx tile (async; lands by end-of-tile barrier)
#pragma unroll
        for (int i = 0; i < 2; ++i) {
            int r = 2 * h + i;
            int sw = 4 * (r & 7);
            GLOAD_LDS4(ixblk + (size_t)r * M_ + m0n + (lane ^ sw), &idxS[cb ^ 1][r * 64]);
        }

        // prefetch NEXT tile's K fragments (consumed next iteration)
        bf16x8 kf_n[4];
#pragma unroll
        for (int ms = 0; ms < 4; ++ms)
            kf_n[ms] = *(const bf16x8*)(Kh + (size_t)(m0n + ms * 16 + lr) * DH_ + lg * 8);

        // V (permuted layout) + mask loads for this tile
        bf16x8 vf[4];
#pragma unroll
        for (int ds = 0; ds < 2; ++ds)
#pragma unroll
            for (int ks = 0; ks < 2; ++ks)
                vf[ds * 2 + ks] = *(const bf16x8*)(Vh + (size_t)(ds * 16 + lr) * M_ + m0 + ks * 32 + lg * 8);
        float4 mkv[4];
#pragma unroll
        for (int ms = 0; ms < 4; ++ms)
            mkv[ms] = *(const float4*)(km + m0 + ms * 16 + 4 * lg);

        // (2) idx (swizzled b128) + Pall gather
        int4 ixv[4];
#pragma unroll
        for (int ms = 0; ms < 4; ++ms)
            ixv[ms] = *(const int4*)&idxS[cb][lr * 64 + ((16 * ms + 4 * lg) ^ swzR)];
        float sv[16];
#pragma unroll
        for (int ms = 0; ms < 4; ++ms) {
            sv[ms * 4 + 0] = (float)PallR[ixv[ms].x];
            sv[ms * 4 + 1] = (float)PallR[ixv[ms].y];
            sv[ms * 4 + 2] = (float)PallR[ixv[ms].z];
            sv[ms * 4 + 3] = (float)PallR[ixv[ms].w];
        }

        // (3) S^T = K @ Q^T (uses kf prefetched last tile; log2 domain)
        f32x4 st[4];
#pragma unroll
        for (int ms = 0; ms < 4; ++ms)
            st[ms] = __builtin_amdgcn_mfma_f32_16x16x32_bf16(kf[ms], qf, z, 0, 0, 0);

#pragma unroll
        for (int ms = 0; ms < 4; ++ms) {
            sv[ms * 4 + 0] = fmaf(mkv[ms].x, LOG2E, st[ms][0] + sv[ms * 4 + 0]);
            sv[ms * 4 + 1] = fmaf(mkv[ms].y, LOG2E, st[ms][1] + sv[ms * 4 + 1]);
            sv[ms * 4 + 2] = fmaf(mkv[ms].z, LOG2E, st[ms][2] + sv[ms * 4 + 2]);
            sv[ms * 4 + 3] = fmaf(mkv[ms].w, LOG2E, st[ms][3] + sv[ms * 4 + 3]);
        }

        // (4) lane-local max (tree) + exec-mask defer check; NO shuffles here
        float t0 = fmaxf(fmaxf(sv[0], sv[1]), fmaxf(sv[2], sv[3]));
        float t1 = fmaxf(fmaxf(sv[4], sv[5]), fmaxf(sv[6], sv[7]));
        float t2 = fmaxf(fmaxf(sv[8], sv[9]), fmaxf(sv[10], sv[11]));
        float t3 = fmaxf(fmaxf(sv[12], sv[13]), fmaxf(sv[14], sv[15]));
        float pmax = fmaxf(fmaxf(t0, t1), fmaxf(t2, t3));

        if (!__all(pmax - mrow <= DTHR)) {   // rare: true row-reduce + rescale
            float rmax = fmaxf(pmax, __shfl_xor(pmax, 16));
            rmax = fmaxf(rmax, __shfl_xor(rmax, 32));
            float mnew = fmaxf(mrow, rmax);
            float alpha = fast_exp2(mrow - mnew);
            mrow = mnew;
            lloc *= alpha;
#pragma unroll
            for (int reg = 0; reg < 4; ++reg) {
                float aB = __shfl(alpha, lg * 4 + reg);
                acc[0][reg] *= aB;
                acc[1][reg] *= aB;
            }
        }

        // (5) exp + per-lane partial sum (tree); reduction deferred to epilogue
        float pq[16];
#pragma unroll
        for (int j = 0; j < 16; ++j) pq[j] = fast_exp2(sv[j] - mrow);
        {
            float s0 = (pq[0] + pq[1]) + (pq[2] + pq[3]);
            float s1 = (pq[4] + pq[5]) + (pq[6] + pq[7]);
            float s2 = (pq[8] + pq[9]) + (pq[10] + pq[11]);
            float s3 = (pq[12] + pq[13]) + (pq[14] + pq[15]);
            lloc += (s0 + s1) + (s2 + s3);
        }

        // (6) PV: pq IS the A-fragment (V stored permuted); no redistribution
#pragma unroll
        for (int ks = 0; ks < 2; ++ks) {
            bf16x8 pf;
#pragma unroll
            for (int e = 0; e < 8; ++e) pf[e] = (__bf16)pq[8 * ks + e];
#pragma unroll
            for (int ds = 0; ds < 2; ++ds)
                acc[ds] = __builtin_amdgcn_mfma_f32_16x16x32_bf16(pf, vf[ds * 2 + ks], acc[ds], 0, 0, 0);
        }

        // (7) one barrier per tile (vmcnt drain covers idx stage + K prefetch)
        __syncthreads();
        cb ^= 1;
#pragma unroll
        for (int ms = 0; ms < 4; ++ms) kf[ms] = kf_n[ms];
    }

    // epilogue: reduce per-lane sums across the 4 row-lanes, then normalize
    float lrow = lloc + __shfl_xor(lloc, 16);
    lrow += __shfl_xor(lrow, 32);
#pragma unroll
    for (int reg = 0; reg < 4; ++reg) {
        float lB = __shfl(lrow, lg * 4 + reg);
        float inv = 1.0f / lB;
        size_t rb = ((size_t)b * N_ + n0 + lg * 4 + reg) * C_ + h * DH_;
        out[rb + lr] = acc[0][reg] * inv;
        out[rb + 16 + lr] = acc[1][reg] * inv;
    }
}

// ---------------- launch ----------------------------------------------------
extern "C" void kernel_launch(void* const* d_in, const int* in_sizes, int n_in,
                              void* d_out, int out_size, void* d_ws, size_t ws_size,
                              hipStream_t stream) {
    const float* Xq = (const float*)d_in[0];
    const float* Xk = (const float*)d_in[1];
    const float* Xv = (const float*)d_in[2];
    const int* ridx = (const int*)d_in[3];
    const float* kmask = (const float*)d_in[4];
    const float* Wq = (const float*)d_in[5];
    const float* bq = (const float*)d_in[6];
    const float* Wk = (const float*)d_in[7];
    const float* bk = (const float*)d_in[8];
    const float* Wv = (const float*)d_in[9];
    const float* bv = (const float*)d_in[10];
    const float* rbank = (const float*)d_in[11];
    float* outp = (float*)d_out;

    char* ws = (char*)d_ws;
    __bf16* Wt = (__bf16*)ws;                               // 393216 B
    __bf16* qb = (__bf16*)(ws + 393216);                    // 4 MB
    __bf16* kb = (__bf16*)(ws + 393216 + 4194304);          // 4 MB
    __bf16* vt = (__bf16*)(ws + 393216 + 8388608);          // 4 MB

    wtrans_kernel<<<dim3(8, 8, 3), dim3(32, 8), 0, stream>>>(Wq, Wk, Wv, Wt);
    proj_kernel<<<dim3(128, 1, 3), 256, 0, stream>>>(Xq, Xk, Xv, bq, bk, bv, Wt, qb, kb, vt);
    attn_kernel<<<512, 512, 0, stream>>>(qb, kb, vt, ridx, kmask, rbank, outp);
}